// Round 10
// baseline (535.944 us; speedup 1.0000x reference)
//
#include <hip/hip_runtime.h>

#define DEVI __device__ __forceinline__

// ---------- helpers ----------
DEVI unsigned fkey(float f) {             // order-preserving float->uint key
  unsigned u = __float_as_uint(f);
  return u ^ ((u >> 31) ? 0xFFFFFFFFu : 0x80000000u);
}
DEVI float funkey(unsigned k) {
  unsigned b = (k & 0x80000000u) ? (k ^ 0x80000000u) : ~k;
  return __uint_as_float(b);
}
DEVI float f4get(const float4& v, int j) {
  return j == 0 ? v.x : j == 1 ? v.y : j == 2 ? v.z : v.w;
}

// ================= CSR build: bucketed counting sort by dst =================
constexpr int BSH = 9;                 // 512 nodes per bucket
constexpr int BNODES = 1 << BSH;
constexpr int PEPT = 16;               // partition: edges per thread
constexpr int PCHUNK = 256 * PEPT;     // 4096 edges per block

__global__ void k_binit(int* __restrict__ bcnt) {
  bcnt[threadIdx.x] = 0;
}

__global__ void k_bcount(const int* __restrict__ dst, int* __restrict__ bcnt,
                         int E, int NB) {
  __shared__ int lh[256];
  lh[threadIdx.x] = 0;
  __syncthreads();
  int stride = gridDim.x * 256;
  for (long i = (long)blockIdx.x * 256 + threadIdx.x; i < E; i += stride)
    atomicAdd(&lh[dst[i] >> BSH], 1);
  __syncthreads();
  if (threadIdx.x < NB && lh[threadIdx.x]) atomicAdd(&bcnt[threadIdx.x], lh[threadIdx.x]);
}

__global__ void k_bscan(const int* __restrict__ bcnt, int* __restrict__ bbase,
                        int* __restrict__ bcur, unsigned* __restrict__ scal, int NB) {
  __shared__ int s[256];
  int t = threadIdx.x;
  int v = (t < NB) ? bcnt[t] : 0;
  s[t] = v;
  __syncthreads();
  for (int o = 1; o < 256; o <<= 1) {
    int add = (t >= o) ? s[t - o] : 0;
    __syncthreads();
    s[t] += add;
    __syncthreads();
  }
  int excl = s[t] - v;
  if (t < NB) { bbase[t] = excl; bcur[t] = excl; }
  if (t == 0) { scal[0] = 0u; scal[1] = 0u; }
}

// pack = (dst&511)<<17 | src  (requires N <= 2^17)
__global__ __launch_bounds__(256)
void k_bpart(const int* __restrict__ src, const int* __restrict__ dst,
             int* __restrict__ bcur, unsigned* __restrict__ epart, int E, int NB) {
  __shared__ int lh[256];
  __shared__ int gbase[256];
  long base = (long)blockIdx.x * PCHUNK;
  lh[threadIdx.x] = 0;
  __syncthreads();
  int ed[PEPT]; int es[PEPT]; unsigned short lpos[PEPT];
#pragma unroll
  for (int j = 0; j < PEPT; j++) {
    long i = base + threadIdx.x + (long)j * 256;   // coalesced
    if (i < E) {
      int d = dst[i];
      es[j] = src[i];
      ed[j] = d;
      lpos[j] = (unsigned short)atomicAdd(&lh[d >> BSH], 1);
    } else {
      ed[j] = -1;
    }
  }
  __syncthreads();
  if (threadIdx.x < NB) {
    int c = lh[threadIdx.x];
    gbase[threadIdx.x] = c ? atomicAdd(&bcur[threadIdx.x], c) : 0;
  }
  __syncthreads();
#pragma unroll
  for (int j = 0; j < PEPT; j++) {
    int d = ed[j];
    if (d >= 0) {
      unsigned p = (unsigned)(gbase[d >> BSH] + (int)lpos[j]);
      epart[p] = ((unsigned)(d & (BNODES - 1)) << 17) | (unsigned)es[j];
    }
  }
}

// one block per bucket: per-node hist + scan -> deg/rowptr/dinv, scatter col
__global__ __launch_bounds__(256)
void k_fine(const unsigned* __restrict__ epart, const int* __restrict__ bbase,
            const int* __restrict__ bcnt, int* __restrict__ rowptr,
            int* __restrict__ deg, float* __restrict__ dinv,
            int* __restrict__ col, int N) {
  __shared__ int lh[BNODES];
  __shared__ int lexcl[BNODES];
  __shared__ int ssc[256];
  int b = blockIdx.x;
  int base = bbase[b], cnt = bcnt[b];
  int nlo = b << BSH;
  int t = threadIdx.x;
  lh[t] = 0; lh[t + 256] = 0;
  __syncthreads();
  for (int i = t; i < cnt; i += 256) {
    unsigned e = epart[base + i];
    atomicAdd(&lh[e >> 17], 1);
  }
  __syncthreads();
  int a0 = lh[2 * t], a1 = lh[2 * t + 1];
  ssc[t] = a0 + a1;
  __syncthreads();
  for (int o = 1; o < 256; o <<= 1) {
    int add = (t >= o) ? ssc[t - o] : 0;
    __syncthreads();
    ssc[t] += add;
    __syncthreads();
  }
  int excl = ssc[t] - (a0 + a1);
  lexcl[2 * t] = excl;
  lexcl[2 * t + 1] = excl + a0;
  __syncthreads();
#pragma unroll
  for (int k = 0; k < 2; k++) {
    int i = t + k * 256;
    int v = nlo + i;
    if (v < N) {
      int dgv = lh[i];
      deg[v] = dgv;
      rowptr[v] = base + lexcl[i];
      dinv[v] = rsqrtf((float)(dgv + 1));
    }
  }
  __syncthreads();
  lh[2 * t] = lexcl[2 * t];
  lh[2 * t + 1] = lexcl[2 * t + 1];
  __syncthreads();
  for (int i = t; i < cnt; i += 256) {
    unsigned e = epart[base + i];
    int p = atomicAdd(&lh[e >> 17], 1);
    col[base + p] = (int)(e & 0x1FFFFu);
  }
}

// ---------- gemm1: x[Nx256] @ W1[256x32], scaled by dinv ----------
// R7: cooperative coalesced staging of x into LDS (double-buffered, prefetch
// overlapped), compute fed from LDS. Fixed the L1-thrash of per-lane-row x
// loads (R4-R6 asymptote ~56us). 256 thr, 128 rows/block, C=8 x R=2 per
// thread, Kc=16, LDS 48KB -> 3 blocks/CU. x slots XOR-swizzled.
__global__ __launch_bounds__(256)
void k_gemm1(const float* __restrict__ in, const float* __restrict__ W,
             const float* __restrict__ dinv, float* __restrict__ out, int N) {
  __shared__ float Wl[256 * 32];          // 32 KB
  __shared__ float xb[2][128 * 16];       // 2 x 8 KB
  const int t = threadIdx.x;

  // ---- stage W (once), coalesced float4 ----
  {
    const float4* W4 = (const float4*)W;
    float4* Wl4 = (float4*)Wl;
#pragma unroll
    for (int i = 0; i < 8; i++) Wl4[t + i * 256] = W4[t + i * 256];
  }

  // staging ids: 2 threads per row, 2 float4 (= 2 swizzled quads) each
  const int srow = t >> 1;                // 0..127
  const int part = t & 1;
  const int sk = (srow >> 1) & 3;         // swizzle key for this row
  long grow = (long)blockIdx.x * 128 + srow;
  const float* gsrc = in + (grow < (long)N ? grow : (long)(N - 1)) * 256 + part * 8;
  const int q0 = part * 2, q1 = part * 2 + 1;
  const int ws0 = srow * 16 + ((q0 ^ sk) << 2);
  const int ws1 = srow * 16 + ((q1 ^ sk) << 2);

  // compute ids: 4 col-groups x 64 row-groups, rows rg and rg+64
  const int cg = t & 3;
  const int rg = t >> 2;                  // 0..63
  const int c0 = cg * 8;
  const int rk = (rg >> 1) & 3;           // rows rg, rg+64 share key (64/2 %4==0)

  // ---- stage chunk 0 ----
  {
    float4 a = *(const float4*)(gsrc + 0);
    float4 b = *(const float4*)(gsrc + 4);
    *(float4*)&xb[0][ws0] = a;
    *(float4*)&xb[0][ws1] = b;
  }
  __syncthreads();

  float acc[2][8];
#pragma unroll
  for (int i = 0; i < 2; i++)
#pragma unroll
    for (int c = 0; c < 8; c++) acc[i][c] = 0.f;

  for (int ch = 0; ch < 16; ch++) {
    float4 na, nb;
    if (ch < 15) {                        // prefetch next chunk into regs
      na = *(const float4*)(gsrc + (ch + 1) * 16 + 0);
      nb = *(const float4*)(gsrc + (ch + 1) * 16 + 4);
    }
    const float* xc = xb[ch & 1];
#pragma unroll
    for (int q = 0; q < 4; q++) {
      float4 xv0 = *(const float4*)&xc[rg * 16 + ((q ^ rk) << 2)];
      float4 xv1 = *(const float4*)&xc[(rg + 64) * 16 + ((q ^ rk) << 2)];
#pragma unroll
      for (int jj = 0; jj < 4; jj++) {
        const float* wr = &Wl[(ch * 16 + q * 4 + jj) * 32 + c0];
        float4 wa = *(const float4*)(wr);
        float4 wb = *(const float4*)(wr + 4);
        float x0 = f4get(xv0, jj);
        float x1 = f4get(xv1, jj);
        acc[0][0] = fmaf(x0, wa.x, acc[0][0]);
        acc[0][1] = fmaf(x0, wa.y, acc[0][1]);
        acc[0][2] = fmaf(x0, wa.z, acc[0][2]);
        acc[0][3] = fmaf(x0, wa.w, acc[0][3]);
        acc[0][4] = fmaf(x0, wb.x, acc[0][4]);
        acc[0][5] = fmaf(x0, wb.y, acc[0][5]);
        acc[0][6] = fmaf(x0, wb.z, acc[0][6]);
        acc[0][7] = fmaf(x0, wb.w, acc[0][7]);
        acc[1][0] = fmaf(x1, wa.x, acc[1][0]);
        acc[1][1] = fmaf(x1, wa.y, acc[1][1]);
        acc[1][2] = fmaf(x1, wa.z, acc[1][2]);
        acc[1][3] = fmaf(x1, wa.w, acc[1][3]);
        acc[1][4] = fmaf(x1, wb.x, acc[1][4]);
        acc[1][5] = fmaf(x1, wb.y, acc[1][5]);
        acc[1][6] = fmaf(x1, wb.z, acc[1][6]);
        acc[1][7] = fmaf(x1, wb.w, acc[1][7]);
      }
    }
    if (ch < 15) {
      __syncthreads();                    // readers of target buffer done
      float* xn = xb[(ch + 1) & 1];
      *(float4*)&xn[ws0] = na;
      *(float4*)&xn[ws1] = nb;
      __syncthreads();                    // writes visible before compute
    }
  }

  // ---- epilogue: scale by dinv, store ----
#pragma unroll
  for (int i = 0; i < 2; i++) {
    long r = (long)blockIdx.x * 128 + rg + i * 64;
    if (r < (long)N) {
      float dv = dinv[r];
      float* op = &out[r * 32 + c0];
      *(float4*)(op) = make_float4(acc[i][0] * dv, acc[i][1] * dv,
                                   acc[i][2] * dv, acc[i][3] * dv);
      *(float4*)(op + 4) = make_float4(acc[i][4] * dv, acc[i][5] * dv,
                                       acc[i][6] * dv, acc[i][7] * dv);
    }
  }
}

// ---------- fused MLP head: s2[Nx32] -> logits[Nx64] ----------
// R14: pipe rebalance. R8-R13 post-mortem: every variant issued ~448
// ds_read_b128/thread (W re-read from LDS each stage = 2/3 of them) ->
// ~27us/CU of LDS-pipe time vs ~13us VALU; waves/CU never exceeded ~5, so
// nothing hid it. Fix: W comes from GLOBAL (L1-resident: 40KB total, <=16KB
// live per stage, shared by all blocks on a CU; 8 distinct f4/wave ->
// coalescer-merged) on the VMEM pipe. LDS keeps only the 32KB xr exchange
// -> 3 barriers (no W staging/swap), 5 blocks/CU capacity (grid 782 =
// 3.05/CU resident = 12 waves/CU). Pipes: VMEM(W) || LDS(xr) || VALU(FMA).
// ROWS=4, cg=8, xr quad-swizzle q^(rg&7), phys row rg+32i (as R8/R12).
__global__ __launch_bounds__(256)
void k_head(const float* __restrict__ s2,
            const float* __restrict__ W2, const float* __restrict__ b2,
            const float* __restrict__ Wo1, const float* __restrict__ bo1,
            const float* __restrict__ Wo2, const float* __restrict__ bo2,
            float* __restrict__ out, int N, unsigned* __restrict__ gmax) {
  __shared__ float xr[128 * 64];      // 32 KB row exchange (z2, then t)
  const int t = threadIdx.x;
  const int cg = t & 7, rg = t >> 3;  // 8 col-groups x 32 row-groups
  const int c0 = cg * 8;
  const int key = rg & 7;
  const long r0 = (long)blockIdx.x * 128 + rg * 4;

  bool rv[4];
  int xrow[4];
#pragma unroll
  for (int i = 0; i < 4; i++) {
    rv[i] = (r0 + i) < (long)N;
    xrow[i] = (rg + 32 * i) * 64;     // phys row base (floats)
  }
  const int q0 = (2 * cg) ^ key, q1 = (2 * cg + 1) ^ key;

  float a1[4][8], a2[4][8];

  // ---- stage 1: a1 = relu(s2 @ W2 + b2) -> xr  (W2 from global/L1) ----
#pragma unroll
  for (int i = 0; i < 4; i++)
#pragma unroll
    for (int c = 0; c < 8; c++) a1[i][c] = 0.f;
  {
    const float* ip = s2 + r0 * 32;
#pragma unroll 2
    for (int k = 0; k < 32; k += 4) {
      float4 xv[4];
#pragma unroll
      for (int i = 0; i < 4; i++)
        xv[i] = rv[i] ? *(const float4*)(ip + i * 32 + k)
                      : make_float4(0.f, 0.f, 0.f, 0.f);
#pragma unroll
      for (int jj = 0; jj < 4; jj++) {
        float4 wa = *(const float4*)&W2[(k + jj) * 64 + c0];
        float4 wb = *(const float4*)&W2[(k + jj) * 64 + c0 + 4];
#pragma unroll
        for (int i = 0; i < 4; i++) {
          float xs = f4get(xv[i], jj);
          a1[i][0] = fmaf(xs, wa.x, a1[i][0]);
          a1[i][1] = fmaf(xs, wa.y, a1[i][1]);
          a1[i][2] = fmaf(xs, wa.z, a1[i][2]);
          a1[i][3] = fmaf(xs, wa.w, a1[i][3]);
          a1[i][4] = fmaf(xs, wb.x, a1[i][4]);
          a1[i][5] = fmaf(xs, wb.y, a1[i][5]);
          a1[i][6] = fmaf(xs, wb.z, a1[i][6]);
          a1[i][7] = fmaf(xs, wb.w, a1[i][7]);
        }
      }
    }
    float bo[8];
#pragma unroll
    for (int c = 0; c < 8; c++) bo[c] = b2[c0 + c];
#pragma unroll
    for (int i = 0; i < 4; i++) {
      float v0 = fmaxf(a1[i][0] + bo[0], 0.f);
      float v1 = fmaxf(a1[i][1] + bo[1], 0.f);
      float v2 = fmaxf(a1[i][2] + bo[2], 0.f);
      float v3 = fmaxf(a1[i][3] + bo[3], 0.f);
      float v4 = fmaxf(a1[i][4] + bo[4], 0.f);
      float v5 = fmaxf(a1[i][5] + bo[5], 0.f);
      float v6 = fmaxf(a1[i][6] + bo[6], 0.f);
      float v7 = fmaxf(a1[i][7] + bo[7], 0.f);
      *(float4*)&xr[xrow[i] + 4 * q0] = make_float4(v0, v1, v2, v3);
      *(float4*)&xr[xrow[i] + 4 * q1] = make_float4(v4, v5, v6, v7);
    }
  }
  __syncthreads();                    // #1: xr(z2) visible

  // ---- stage 2: a2 = relu(z2 @ Wo1 + bo1)  (Wo1 from global/L1) ----
#pragma unroll
  for (int i = 0; i < 4; i++)
#pragma unroll
    for (int c = 0; c < 8; c++) a2[i][c] = 0.f;
#pragma unroll 2
  for (int k = 0; k < 64; k += 4) {
    const int q = k >> 2;
    float4 xv[4];
#pragma unroll
    for (int i = 0; i < 4; i++)
      xv[i] = *(const float4*)&xr[xrow[i] + 4 * (q ^ key)];
#pragma unroll
    for (int jj = 0; jj < 4; jj++) {
      float4 wa = *(const float4*)&Wo1[(k + jj) * 64 + c0];
      float4 wb = *(const float4*)&Wo1[(k + jj) * 64 + c0 + 4];
#pragma unroll
      for (int i = 0; i < 4; i++) {
        float xs = f4get(xv[i], jj);
        a2[i][0] = fmaf(xs, wa.x, a2[i][0]);
        a2[i][1] = fmaf(xs, wa.y, a2[i][1]);
        a2[i][2] = fmaf(xs, wa.z, a2[i][2]);
        a2[i][3] = fmaf(xs, wa.w, a2[i][3]);
        a2[i][4] = fmaf(xs, wb.x, a2[i][4]);
        a2[i][5] = fmaf(xs, wb.y, a2[i][5]);
        a2[i][6] = fmaf(xs, wb.z, a2[i][6]);
        a2[i][7] = fmaf(xs, wb.w, a2[i][7]);
      }
    }
  }
  __syncthreads();                    // #2: xr(z2) reads done

  {  // t (relu+bo1) -> xr
    float bo[8];
#pragma unroll
    for (int c = 0; c < 8; c++) bo[c] = bo1[c0 + c];
#pragma unroll
    for (int i = 0; i < 4; i++) {
      float v0 = fmaxf(a2[i][0] + bo[0], 0.f);
      float v1 = fmaxf(a2[i][1] + bo[1], 0.f);
      float v2 = fmaxf(a2[i][2] + bo[2], 0.f);
      float v3 = fmaxf(a2[i][3] + bo[3], 0.f);
      float v4 = fmaxf(a2[i][4] + bo[4], 0.f);
      float v5 = fmaxf(a2[i][5] + bo[5], 0.f);
      float v6 = fmaxf(a2[i][6] + bo[6], 0.f);
      float v7 = fmaxf(a2[i][7] + bo[7], 0.f);
      *(float4*)&xr[xrow[i] + 4 * q0] = make_float4(v0, v1, v2, v3);
      *(float4*)&xr[xrow[i] + 4 * q1] = make_float4(v4, v5, v6, v7);
    }
  }
  __syncthreads();                    // #3: xr(t) visible

  // ---- stage 3: logits = t @ Wo2 + bo2  (Wo2 from global/L1) ----
#pragma unroll
  for (int i = 0; i < 4; i++)
#pragma unroll
    for (int c = 0; c < 8; c++) a1[i][c] = 0.f;
#pragma unroll 2
  for (int k = 0; k < 64; k += 4) {
    const int q = k >> 2;
    float4 xv[4];
#pragma unroll
    for (int i = 0; i < 4; i++)
      xv[i] = *(const float4*)&xr[xrow[i] + 4 * (q ^ key)];
#pragma unroll
    for (int jj = 0; jj < 4; jj++) {
      float4 wa = *(const float4*)&Wo2[(k + jj) * 64 + c0];
      float4 wb = *(const float4*)&Wo2[(k + jj) * 64 + c0 + 4];
#pragma unroll
      for (int i = 0; i < 4; i++) {
        float xs = f4get(xv[i], jj);
        a1[i][0] = fmaf(xs, wa.x, a1[i][0]);
        a1[i][1] = fmaf(xs, wa.y, a1[i][1]);
        a1[i][2] = fmaf(xs, wa.z, a1[i][2]);
        a1[i][3] = fmaf(xs, wa.w, a1[i][3]);
        a1[i][4] = fmaf(xs, wb.x, a1[i][4]);
        a1[i][5] = fmaf(xs, wb.y, a1[i][5]);
        a1[i][6] = fmaf(xs, wb.z, a1[i][6]);
        a1[i][7] = fmaf(xs, wb.w, a1[i][7]);
      }
    }
  }

  // epilogue: + bo2, global max, store
  float m = -3.4e38f;
  {
    float bo[8];
#pragma unroll
    for (int c = 0; c < 8; c++) bo[c] = bo2[c0 + c];
#pragma unroll
    for (int i = 0; i < 4; i++) {
      if (!rv[i]) continue;
      float o[8];
#pragma unroll
      for (int c = 0; c < 8; c++) {
        float v = a1[i][c] + bo[c];
        m = fmaxf(m, v);
        o[c] = v;
      }
      float* op = &out[(r0 + i) * 64 + c0];
      *(float4*)(op) = make_float4(o[0], o[1], o[2], o[3]);
      *(float4*)(op + 4) = make_float4(o[4], o[5], o[6], o[7]);
    }
  }
  // wave-level max reduce, one atomic per wave (no LDS scratch)
#pragma unroll
  for (int o2 = 1; o2 < 64; o2 <<= 1) m = fmaxf(m, __shfl_xor(m, o2, 64));
  if ((t & 63) == 0) atomicMax(gmax, fkey(m));
}

// ---------- GCN aggregation (float4 lanes) ----------
template <int FEAT, bool BIAS, bool RELU, bool PSCALE>
__launch_bounds__(256)
__global__ void k_aggv(const float* __restrict__ g, const int* __restrict__ col,
                       const int* __restrict__ rowptr, const int* __restrict__ deg,
                       const float* __restrict__ dinv, const float* __restrict__ bias,
                       float* __restrict__ out, int N) {
  constexpr int LPN = FEAT / 4;       // lanes per node (float4 each)
  constexpr int NPB = 256 / LPN;      // nodes per block
  int nib = threadIdx.x / LPN;
  int c = threadIdx.x % LPN;
  long v = (long)blockIdx.x * NPB + nib;
  if (v >= N) return;

  const float4* g4 = (const float4*)g;
  float4 acc = g4[v * LPN + c];       // self-loop term
  int start = rowptr[v], dg = deg[v];
  int e = 0;
  while (e < dg) {
    int cnt = min(LPN, dg - e);
    int idx = (c < cnt) ? col[start + e + c] : 0;
    int j = 0;
    for (; j + 4 <= cnt; j += 4) {    // 4 independent 16B gathers in flight
      int u0 = __shfl(idx, j + 0, LPN);
      int u1 = __shfl(idx, j + 1, LPN);
      int u2 = __shfl(idx, j + 2, LPN);
      int u3 = __shfl(idx, j + 3, LPN);
      float4 a0 = g4[(long)u0 * LPN + c];
      float4 a1 = g4[(long)u1 * LPN + c];
      float4 a2 = g4[(long)u2 * LPN + c];
      float4 a3 = g4[(long)u3 * LPN + c];
      acc.x += (a0.x + a1.x) + (a2.x + a3.x);
      acc.y += (a0.y + a1.y) + (a2.y + a3.y);
      acc.z += (a0.z + a1.z) + (a2.z + a3.z);
      acc.w += (a0.w + a1.w) + (a2.w + a3.w);
    }
    for (; j < cnt; j++) {
      int u = __shfl(idx, j, LPN);
      float4 a = g4[(long)u * LPN + c];
      acc.x += a.x; acc.y += a.y; acc.z += a.z; acc.w += a.w;
    }
    e += cnt;
  }
  float dv = dinv[v];
  float4 val;
  val.x = acc.x * dv; val.y = acc.y * dv; val.z = acc.z * dv; val.w = acc.w * dv;
  if (BIAS) {
    float4 b = ((const float4*)bias)[c];
    val.x += b.x; val.y += b.y; val.z += b.z; val.w += b.w;
  }
  if (RELU) {
    val.x = fmaxf(val.x, 0.f); val.y = fmaxf(val.y, 0.f);
    val.z = fmaxf(val.z, 0.f); val.w = fmaxf(val.w, 0.f);
  }
  if (PSCALE) {
    val.x *= dv; val.y *= dv; val.z *= dv; val.w *= dv;
  }
  ((float4*)out)[v * LPN + c] = val;
}

// ---------- softmax ----------
__global__ void k_smsum(const float* __restrict__ logit, unsigned* __restrict__ scal, int total) {
  __shared__ float s[256];
  float gmax = funkey(scal[0]);
  float loc = 0.f;
  for (int i = blockIdx.x * 256 + threadIdx.x; i < total; i += gridDim.x * 256)
    loc += expf(logit[i] - gmax);
  s[threadIdx.x] = loc; __syncthreads();
  for (int o = 128; o > 0; o >>= 1) {
    if (threadIdx.x < o) s[threadIdx.x] += s[threadIdx.x + o];
    __syncthreads();
  }
  if (threadIdx.x == 0) atomicAdd((float*)&scal[1], s[0]);
}

__global__ void k_smnorm(float* __restrict__ logit, const unsigned* __restrict__ scal, int total) {
  float gmax = funkey(scal[0]);
  float inv = 1.0f / __uint_as_float(scal[1]);
  int i = blockIdx.x * 256 + threadIdx.x;
  if (i < total) logit[i] = expf(logit[i] - gmax) * inv;
}

// ---------- launch ----------
extern "C" void kernel_launch(void* const* d_in, const int* in_sizes, int n_in,
                              void* d_out, int out_size, void* d_ws, size_t ws_size,
                              hipStream_t stream) {
  const float* x   = (const float*)d_in[0];
  const int*   ei  = (const int*)d_in[1];
  const float* W1  = (const float*)d_in[3];
  const float* b1  = (const float*)d_in[4];
  const float* W2  = (const float*)d_in[5];
  const float* b2  = (const float*)d_in[6];
  const float* Wo1 = (const float*)d_in[7];
  const float* bo1 = (const float*)d_in[8];
  const float* Wo2 = (const float*)d_in[9];
  const float* bo2 = (const float*)d_in[10];

  const int N = in_sizes[0] / 256;   // in_dim = 256
  const int E = in_sizes[1] / 2;
  const int* src = ei;
  const int* dst = ei + E;
  const int NB = (N + BNODES - 1) / BNODES;

  size_t o = 0;
  auto carve = [&](size_t bytes) -> char* {
    char* p = (char*)d_ws + o;
    o += (bytes + 255) & ~(size_t)255;
    return p;
  };
  float* R1     = (float*)carve((size_t)N * 64 * 4);  // g1 | s2
  float* R2     = (float*)carve((size_t)N * 64 * 4);  // epart | p
  int*   col    = (int*)carve((size_t)E * 4);
  int*   deg    = (int*)carve((size_t)N * 4);
  float* dinv   = (float*)carve((size_t)N * 4);
  int*   rowptr = (int*)carve((size_t)N * 4);
  int*   bcnt   = (int*)carve(256 * 4);
  int*   bbase  = (int*)carve(256 * 4);
  int*   bcur   = (int*)carve(256 * 4);
  unsigned* scal = (unsigned*)carve(64);

  unsigned* epart = (unsigned*)R2;  // dead before p is written
  float* g1 = R1;   // N x 32
  float* p  = R2;   // N x 32: dinv .* relu(layer-1 out)
  float* s2 = R1;   // N x 32: aggregated p (g1 dead)
  float* logits = (float*)d_out;

  // ---- CSR build ----
  k_binit<<<1, 256, 0, stream>>>(bcnt);
  k_bcount<<<512, 256, 0, stream>>>(dst, bcnt, E, NB);
  k_bscan<<<1, 256, 0, stream>>>(bcnt, bbase, bcur, scal, NB);
  k_bpart<<<(E + PCHUNK - 1) / PCHUNK, 256, 0, stream>>>(src, dst, bcur, epart, E, NB);
  k_fine<<<NB, 256, 0, stream>>>(epart, bbase, bcnt, rowptr, deg, dinv, col, N);

  const int g1G = (N + 127) / 128;  // gemm1 / head: 128 rows per block
  const int gA  = (N + 31) / 32;    // agg32: 32 nodes per block

  // layer 1: g1 = dinv .* (x @ W1); p = dinv .* relu(b1 + dinv*(g1[v]+sum g1[u]))
  k_gemm1<<<g1G, 256, 0, stream>>>(x, W1, dinv, g1, N);
  k_aggv<32, true, true, true><<<gA, 256, 0, stream>>>(g1, col, rowptr, deg, dinv, b1, p, N);

  // layer 2 (aggregation commuted before W2): s2 = dinv*(p[v]+sum p[u])
  k_aggv<32, false, false, false><<<gA, 256, 0, stream>>>(p, col, rowptr, deg, dinv, nullptr, s2, N);

  // fused MLP head: s2 -> logits (tracks global max in scal[0])
  k_head<<<g1G, 256, 0, stream>>>(s2, W2, b2, Wo1, bo1, Wo2, bo2, logits, N, scal);

  // softmax over all N*64 logits
  k_smsum<<<1024, 256, 0, stream>>>(logits, scal, out_size);
  k_smnorm<<<(out_size + 255) / 256, 256, 0, stream>>>(logits, scal, out_size);
}

// Round 11
// 479.541 us; speedup vs baseline: 1.1176x; 1.1176x over previous
//
#include <hip/hip_runtime.h>

#define DEVI __device__ __forceinline__

// ---------- helpers ----------
DEVI unsigned fkey(float f) {             // order-preserving float->uint key
  unsigned u = __float_as_uint(f);
  return u ^ ((u >> 31) ? 0xFFFFFFFFu : 0x80000000u);
}
DEVI float funkey(unsigned k) {
  unsigned b = (k & 0x80000000u) ? (k ^ 0x80000000u) : ~k;
  return __uint_as_float(b);
}
DEVI float f4get(const float4& v, int j) {
  return j == 0 ? v.x : j == 1 ? v.y : j == 2 ? v.z : v.w;
}

// ================= CSR build: bucketed counting sort by dst =================
constexpr int BSH = 9;                 // 512 nodes per bucket
constexpr int BNODES = 1 << BSH;
constexpr int PEPT = 16;               // partition: edges per thread
constexpr int PCHUNK = 256 * PEPT;     // 4096 edges per block

__global__ void k_binit(int* __restrict__ bcnt) {
  bcnt[threadIdx.x] = 0;
}

__global__ void k_bcount(const int* __restrict__ dst, int* __restrict__ bcnt,
                         int E, int NB) {
  __shared__ int lh[256];
  lh[threadIdx.x] = 0;
  __syncthreads();
  int stride = gridDim.x * 256;
  for (long i = (long)blockIdx.x * 256 + threadIdx.x; i < E; i += stride)
    atomicAdd(&lh[dst[i] >> BSH], 1);
  __syncthreads();
  if (threadIdx.x < NB && lh[threadIdx.x]) atomicAdd(&bcnt[threadIdx.x], lh[threadIdx.x]);
}

__global__ void k_bscan(const int* __restrict__ bcnt, int* __restrict__ bbase,
                        int* __restrict__ bcur, unsigned* __restrict__ scal, int NB) {
  __shared__ int s[256];
  int t = threadIdx.x;
  int v = (t < NB) ? bcnt[t] : 0;
  s[t] = v;
  __syncthreads();
  for (int o = 1; o < 256; o <<= 1) {
    int add = (t >= o) ? s[t - o] : 0;
    __syncthreads();
    s[t] += add;
    __syncthreads();
  }
  int excl = s[t] - v;
  if (t < NB) { bbase[t] = excl; bcur[t] = excl; }
  if (t == 0) { scal[0] = 0u; scal[1] = 0u; }
}

// pack = (dst&511)<<17 | src  (requires N <= 2^17)
__global__ __launch_bounds__(256)
void k_bpart(const int* __restrict__ src, const int* __restrict__ dst,
             int* __restrict__ bcur, unsigned* __restrict__ epart, int E, int NB) {
  __shared__ int lh[256];
  __shared__ int gbase[256];
  long base = (long)blockIdx.x * PCHUNK;
  lh[threadIdx.x] = 0;
  __syncthreads();
  int ed[PEPT]; int es[PEPT]; unsigned short lpos[PEPT];
#pragma unroll
  for (int j = 0; j < PEPT; j++) {
    long i = base + threadIdx.x + (long)j * 256;   // coalesced
    if (i < E) {
      int d = dst[i];
      es[j] = src[i];
      ed[j] = d;
      lpos[j] = (unsigned short)atomicAdd(&lh[d >> BSH], 1);
    } else {
      ed[j] = -1;
    }
  }
  __syncthreads();
  if (threadIdx.x < NB) {
    int c = lh[threadIdx.x];
    gbase[threadIdx.x] = c ? atomicAdd(&bcur[threadIdx.x], c) : 0;
  }
  __syncthreads();
#pragma unroll
  for (int j = 0; j < PEPT; j++) {
    int d = ed[j];
    if (d >= 0) {
      unsigned p = (unsigned)(gbase[d >> BSH] + (int)lpos[j]);
      epart[p] = ((unsigned)(d & (BNODES - 1)) << 17) | (unsigned)es[j];
    }
  }
}

// one block per bucket: per-node hist + scan -> deg/rowptr/dinv, scatter col
__global__ __launch_bounds__(256)
void k_fine(const unsigned* __restrict__ epart, const int* __restrict__ bbase,
            const int* __restrict__ bcnt, int* __restrict__ rowptr,
            int* __restrict__ deg, float* __restrict__ dinv,
            int* __restrict__ col, int N) {
  __shared__ int lh[BNODES];
  __shared__ int lexcl[BNODES];
  __shared__ int ssc[256];
  int b = blockIdx.x;
  int base = bbase[b], cnt = bcnt[b];
  int nlo = b << BSH;
  int t = threadIdx.x;
  lh[t] = 0; lh[t + 256] = 0;
  __syncthreads();
  for (int i = t; i < cnt; i += 256) {
    unsigned e = epart[base + i];
    atomicAdd(&lh[e >> 17], 1);
  }
  __syncthreads();
  int a0 = lh[2 * t], a1 = lh[2 * t + 1];
  ssc[t] = a0 + a1;
  __syncthreads();
  for (int o = 1; o < 256; o <<= 1) {
    int add = (t >= o) ? ssc[t - o] : 0;
    __syncthreads();
    ssc[t] += add;
    __syncthreads();
  }
  int excl = ssc[t] - (a0 + a1);
  lexcl[2 * t] = excl;
  lexcl[2 * t + 1] = excl + a0;
  __syncthreads();
#pragma unroll
  for (int k = 0; k < 2; k++) {
    int i = t + k * 256;
    int v = nlo + i;
    if (v < N) {
      int dgv = lh[i];
      deg[v] = dgv;
      rowptr[v] = base + lexcl[i];
      dinv[v] = rsqrtf((float)(dgv + 1));
    }
  }
  __syncthreads();
  lh[2 * t] = lexcl[2 * t];
  lh[2 * t + 1] = lexcl[2 * t + 1];
  __syncthreads();
  for (int i = t; i < cnt; i += 256) {
    unsigned e = epart[base + i];
    int p = atomicAdd(&lh[e >> 17], 1);
    col[base + p] = (int)(e & 0x1FFFFu);
  }
}

// ---------- gemm1: x[Nx256] @ W1[256x32], scaled by dinv ----------
// R7: cooperative coalesced staging of x into LDS (double-buffered, prefetch
// overlapped), compute fed from LDS. Fixed the L1-thrash of per-lane-row x
// loads (R4-R6 asymptote ~56us). 256 thr, 128 rows/block, C=8 x R=2 per
// thread, Kc=16, LDS 48KB -> 3 blocks/CU. x slots XOR-swizzled.
__global__ __launch_bounds__(256)
void k_gemm1(const float* __restrict__ in, const float* __restrict__ W,
             const float* __restrict__ dinv, float* __restrict__ out, int N) {
  __shared__ float Wl[256 * 32];          // 32 KB
  __shared__ float xb[2][128 * 16];       // 2 x 8 KB
  const int t = threadIdx.x;

  // ---- stage W (once), coalesced float4 ----
  {
    const float4* W4 = (const float4*)W;
    float4* Wl4 = (float4*)Wl;
#pragma unroll
    for (int i = 0; i < 8; i++) Wl4[t + i * 256] = W4[t + i * 256];
  }

  // staging ids: 2 threads per row, 2 float4 (= 2 swizzled quads) each
  const int srow = t >> 1;                // 0..127
  const int part = t & 1;
  const int sk = (srow >> 1) & 3;         // swizzle key for this row
  long grow = (long)blockIdx.x * 128 + srow;
  const float* gsrc = in + (grow < (long)N ? grow : (long)(N - 1)) * 256 + part * 8;
  const int q0 = part * 2, q1 = part * 2 + 1;
  const int ws0 = srow * 16 + ((q0 ^ sk) << 2);
  const int ws1 = srow * 16 + ((q1 ^ sk) << 2);

  // compute ids: 4 col-groups x 64 row-groups, rows rg and rg+64
  const int cg = t & 3;
  const int rg = t >> 2;                  // 0..63
  const int c0 = cg * 8;
  const int rk = (rg >> 1) & 3;           // rows rg, rg+64 share key (64/2 %4==0)

  // ---- stage chunk 0 ----
  {
    float4 a = *(const float4*)(gsrc + 0);
    float4 b = *(const float4*)(gsrc + 4);
    *(float4*)&xb[0][ws0] = a;
    *(float4*)&xb[0][ws1] = b;
  }
  __syncthreads();

  float acc[2][8];
#pragma unroll
  for (int i = 0; i < 2; i++)
#pragma unroll
    for (int c = 0; c < 8; c++) acc[i][c] = 0.f;

  for (int ch = 0; ch < 16; ch++) {
    float4 na, nb;
    if (ch < 15) {                        // prefetch next chunk into regs
      na = *(const float4*)(gsrc + (ch + 1) * 16 + 0);
      nb = *(const float4*)(gsrc + (ch + 1) * 16 + 4);
    }
    const float* xc = xb[ch & 1];
#pragma unroll
    for (int q = 0; q < 4; q++) {
      float4 xv0 = *(const float4*)&xc[rg * 16 + ((q ^ rk) << 2)];
      float4 xv1 = *(const float4*)&xc[(rg + 64) * 16 + ((q ^ rk) << 2)];
#pragma unroll
      for (int jj = 0; jj < 4; jj++) {
        const float* wr = &Wl[(ch * 16 + q * 4 + jj) * 32 + c0];
        float4 wa = *(const float4*)(wr);
        float4 wb = *(const float4*)(wr + 4);
        float x0 = f4get(xv0, jj);
        float x1 = f4get(xv1, jj);
        acc[0][0] = fmaf(x0, wa.x, acc[0][0]);
        acc[0][1] = fmaf(x0, wa.y, acc[0][1]);
        acc[0][2] = fmaf(x0, wa.z, acc[0][2]);
        acc[0][3] = fmaf(x0, wa.w, acc[0][3]);
        acc[0][4] = fmaf(x0, wb.x, acc[0][4]);
        acc[0][5] = fmaf(x0, wb.y, acc[0][5]);
        acc[0][6] = fmaf(x0, wb.z, acc[0][6]);
        acc[0][7] = fmaf(x0, wb.w, acc[0][7]);
        acc[1][0] = fmaf(x1, wa.x, acc[1][0]);
        acc[1][1] = fmaf(x1, wa.y, acc[1][1]);
        acc[1][2] = fmaf(x1, wa.z, acc[1][2]);
        acc[1][3] = fmaf(x1, wa.w, acc[1][3]);
        acc[1][4] = fmaf(x1, wb.x, acc[1][4]);
        acc[1][5] = fmaf(x1, wb.y, acc[1][5]);
        acc[1][6] = fmaf(x1, wb.z, acc[1][6]);
        acc[1][7] = fmaf(x1, wb.w, acc[1][7]);
      }
    }
    if (ch < 15) {
      __syncthreads();                    // readers of target buffer done
      float* xn = xb[(ch + 1) & 1];
      *(float4*)&xn[ws0] = na;
      *(float4*)&xn[ws1] = nb;
      __syncthreads();                    // writes visible before compute
    }
  }

  // ---- epilogue: scale by dinv, store ----
#pragma unroll
  for (int i = 0; i < 2; i++) {
    long r = (long)blockIdx.x * 128 + rg + i * 64;
    if (r < (long)N) {
      float dv = dinv[r];
      float* op = &out[r * 32 + c0];
      *(float4*)(op) = make_float4(acc[i][0] * dv, acc[i][1] * dv,
                                   acc[i][2] * dv, acc[i][3] * dv);
      *(float4*)(op + 4) = make_float4(acc[i][4] * dv, acc[i][5] * dv,
                                       acc[i][6] * dv, acc[i][7] * dv);
    }
  }
}

// ---------- fused MLP head: s2[Nx32] -> logits[Nx64] ----------
// R15 = exact R8 core (the best measured head: 63us; ROWS=4, separate B
// buffer for Wo1 -> no mid-kernel write-bubble, 4 barriers, 128 rows/block)
// with a cheaper epilogue: per-block online-softmax stats {lm, sum} via
// wave-shfl + 3 barriers (replaces R8's 9-barrier tree + contended global
// atomicMax). k_smfin folds the 782 pairs; k_smsum (25.6MB pass) deleted.
// R14 post-mortem: W MUST be in LDS (global W reads = exposed VMEM latency
// in the FMA chain, 104us). xr quad-swizzle q^(rg&7), phys row rg+32i.
__global__ __launch_bounds__(256)
void k_head(const float* __restrict__ s2,
            const float* __restrict__ W2, const float* __restrict__ b2,
            const float* __restrict__ Wo1, const float* __restrict__ bo1,
            const float* __restrict__ Wo2, const float* __restrict__ bo2,
            float* __restrict__ out, int N, float* __restrict__ bstat) {
  __shared__ float A[64 * 64];        // 16 KB: W2 (2048 used) -> Wo2
  __shared__ float B[64 * 64];        // 16 KB: Wo1
  __shared__ float xr[128 * 64];      // 32 KB row exchange (z2, then t)
  const int t = threadIdx.x;
  const int cg = t & 7, rg = t >> 3;  // 8 col-groups x 32 row-groups
  const int c0 = cg * 8;
  const int key = rg & 7;
  const long r0 = (long)blockIdx.x * 128 + rg * 4;

  {  // stage W2 -> A (2048 floats), Wo1 -> B (4096 floats)
    const float4* w2 = (const float4*)W2;
    const float4* w1 = (const float4*)Wo1;
    float4* Af = (float4*)A;
    float4* Bf = (float4*)B;
    Af[t] = w2[t];
    Af[t + 256] = w2[t + 256];
#pragma unroll
    for (int i = 0; i < 4; i++) Bf[t + i * 256] = w1[t + i * 256];
  }
  __syncthreads();                    // #1: A(W2), B(Wo1) visible

  bool rv[4];
  int xrow[4];
#pragma unroll
  for (int i = 0; i < 4; i++) {
    rv[i] = (r0 + i) < (long)N;
    xrow[i] = (rg + 32 * i) * 64;     // phys row base (floats)
  }
  const int q0 = (2 * cg) ^ key, q1 = (2 * cg + 1) ^ key;

  float a1[4][8], a2[4][8];

  // ---- stage 1: a1 = relu(s2 @ W2 + b2) -> xr ----
#pragma unroll
  for (int i = 0; i < 4; i++)
#pragma unroll
    for (int c = 0; c < 8; c++) a1[i][c] = 0.f;
  {
    const float* ip = s2 + r0 * 32;
#pragma unroll 2
    for (int k = 0; k < 32; k += 4) {
      float4 xv[4];
#pragma unroll
      for (int i = 0; i < 4; i++)
        xv[i] = rv[i] ? *(const float4*)(ip + i * 32 + k)
                      : make_float4(0.f, 0.f, 0.f, 0.f);
#pragma unroll
      for (int jj = 0; jj < 4; jj++) {
        float4 wa = *(const float4*)&A[(k + jj) * 64 + c0];
        float4 wb = *(const float4*)&A[(k + jj) * 64 + c0 + 4];
#pragma unroll
        for (int i = 0; i < 4; i++) {
          float xs = f4get(xv[i], jj);
          a1[i][0] = fmaf(xs, wa.x, a1[i][0]);
          a1[i][1] = fmaf(xs, wa.y, a1[i][1]);
          a1[i][2] = fmaf(xs, wa.z, a1[i][2]);
          a1[i][3] = fmaf(xs, wa.w, a1[i][3]);
          a1[i][4] = fmaf(xs, wb.x, a1[i][4]);
          a1[i][5] = fmaf(xs, wb.y, a1[i][5]);
          a1[i][6] = fmaf(xs, wb.z, a1[i][6]);
          a1[i][7] = fmaf(xs, wb.w, a1[i][7]);
        }
      }
    }
    float bo[8];
#pragma unroll
    for (int c = 0; c < 8; c++) bo[c] = b2[c0 + c];
#pragma unroll
    for (int i = 0; i < 4; i++) {
      float v0 = fmaxf(a1[i][0] + bo[0], 0.f);
      float v1 = fmaxf(a1[i][1] + bo[1], 0.f);
      float v2 = fmaxf(a1[i][2] + bo[2], 0.f);
      float v3 = fmaxf(a1[i][3] + bo[3], 0.f);
      float v4 = fmaxf(a1[i][4] + bo[4], 0.f);
      float v5 = fmaxf(a1[i][5] + bo[5], 0.f);
      float v6 = fmaxf(a1[i][6] + bo[6], 0.f);
      float v7 = fmaxf(a1[i][7] + bo[7], 0.f);
      *(float4*)&xr[xrow[i] + 4 * q0] = make_float4(v0, v1, v2, v3);
      *(float4*)&xr[xrow[i] + 4 * q1] = make_float4(v4, v5, v6, v7);
    }
  }
  __syncthreads();                    // #2: xr(z2) visible

  // prefetch Wo2 into regs (in flight under stage 2)
  float4 wn[4];
  {
    const float4* w = (const float4*)Wo2;
#pragma unroll
    for (int i = 0; i < 4; i++) wn[i] = w[t + i * 256];
  }

  // ---- stage 2: a2 = relu(z2 @ Wo1 + bo1), reads B + xr ----
#pragma unroll
  for (int i = 0; i < 4; i++)
#pragma unroll
    for (int c = 0; c < 8; c++) a2[i][c] = 0.f;
#pragma unroll 2
  for (int k = 0; k < 64; k += 4) {
    const int q = k >> 2;
    float4 xv[4];
#pragma unroll
    for (int i = 0; i < 4; i++)
      xv[i] = *(const float4*)&xr[xrow[i] + 4 * (q ^ key)];
#pragma unroll
    for (int jj = 0; jj < 4; jj++) {
      float4 wa = *(const float4*)&B[(k + jj) * 64 + c0];
      float4 wb = *(const float4*)&B[(k + jj) * 64 + c0 + 4];
#pragma unroll
      for (int i = 0; i < 4; i++) {
        float xs = f4get(xv[i], jj);
        a2[i][0] = fmaf(xs, wa.x, a2[i][0]);
        a2[i][1] = fmaf(xs, wa.y, a2[i][1]);
        a2[i][2] = fmaf(xs, wa.z, a2[i][2]);
        a2[i][3] = fmaf(xs, wa.w, a2[i][3]);
        a2[i][4] = fmaf(xs, wb.x, a2[i][4]);
        a2[i][5] = fmaf(xs, wb.y, a2[i][5]);
        a2[i][6] = fmaf(xs, wb.z, a2[i][6]);
        a2[i][7] = fmaf(xs, wb.w, a2[i][7]);
      }
    }
  }
  __syncthreads();                    // #3: xr(z2) reads done

  {  // Wo2 regs -> A; t (relu+bo1) -> xr
    float4* Af = (float4*)A;
#pragma unroll
    for (int i = 0; i < 4; i++) Af[t + i * 256] = wn[i];
    float bo[8];
#pragma unroll
    for (int c = 0; c < 8; c++) bo[c] = bo1[c0 + c];
#pragma unroll
    for (int i = 0; i < 4; i++) {
      float v0 = fmaxf(a2[i][0] + bo[0], 0.f);
      float v1 = fmaxf(a2[i][1] + bo[1], 0.f);
      float v2 = fmaxf(a2[i][2] + bo[2], 0.f);
      float v3 = fmaxf(a2[i][3] + bo[3], 0.f);
      float v4 = fmaxf(a2[i][4] + bo[4], 0.f);
      float v5 = fmaxf(a2[i][5] + bo[5], 0.f);
      float v6 = fmaxf(a2[i][6] + bo[6], 0.f);
      float v7 = fmaxf(a2[i][7] + bo[7], 0.f);
      *(float4*)&xr[xrow[i] + 4 * q0] = make_float4(v0, v1, v2, v3);
      *(float4*)&xr[xrow[i] + 4 * q1] = make_float4(v4, v5, v6, v7);
    }
  }
  __syncthreads();                    // #4: xr(t)+A(Wo2) visible

  // ---- stage 3: logits = t @ Wo2 + bo2 (reuse a1 as acc) ----
#pragma unroll
  for (int i = 0; i < 4; i++)
#pragma unroll
    for (int c = 0; c < 8; c++) a1[i][c] = 0.f;
#pragma unroll 2
  for (int k = 0; k < 64; k += 4) {
    const int q = k >> 2;
    float4 xv[4];
#pragma unroll
    for (int i = 0; i < 4; i++)
      xv[i] = *(const float4*)&xr[xrow[i] + 4 * (q ^ key)];
#pragma unroll
    for (int jj = 0; jj < 4; jj++) {
      float4 wa = *(const float4*)&A[(k + jj) * 64 + c0];
      float4 wb = *(const float4*)&A[(k + jj) * 64 + c0 + 4];
#pragma unroll
      for (int i = 0; i < 4; i++) {
        float xs = f4get(xv[i], jj);
        a1[i][0] = fmaf(xs, wa.x, a1[i][0]);
        a1[i][1] = fmaf(xs, wa.y, a1[i][1]);
        a1[i][2] = fmaf(xs, wa.z, a1[i][2]);
        a1[i][3] = fmaf(xs, wa.w, a1[i][3]);
        a1[i][4] = fmaf(xs, wb.x, a1[i][4]);
        a1[i][5] = fmaf(xs, wb.y, a1[i][5]);
        a1[i][6] = fmaf(xs, wb.z, a1[i][6]);
        a1[i][7] = fmaf(xs, wb.w, a1[i][7]);
      }
    }
  }

  // epilogue: + bo2, store, per-block online-softmax stats {lm, sum}
  float bo[8];
#pragma unroll
  for (int c = 0; c < 8; c++) bo[c] = bo2[c0 + c];
  float m = -3.4e38f;
#pragma unroll
  for (int i = 0; i < 4; i++) {
    if (!rv[i]) continue;
    float o[8];
#pragma unroll
    for (int c = 0; c < 8; c++) {
      float v = a1[i][c] + bo[c];
      m = fmaxf(m, v);
      o[c] = v;
    }
    float* op = &out[(r0 + i) * 64 + c0];
    *(float4*)(op) = make_float4(o[0], o[1], o[2], o[3]);
    *(float4*)(op + 4) = make_float4(o[4], o[5], o[6], o[7]);
  }
  // wave max -> block max (xr free after a barrier)
#pragma unroll
  for (int o2 = 1; o2 < 64; o2 <<= 1) m = fmaxf(m, __shfl_xor(m, o2, 64));
  __syncthreads();                    // all stage-3 xr reads done
  if ((t & 63) == 0) xr[t >> 6] = m;
  __syncthreads();
  const float lm = fmaxf(fmaxf(xr[0], xr[1]), fmaxf(xr[2], xr[3]));
  float ls = 0.f;
#pragma unroll
  for (int i = 0; i < 4; i++) {
    if (!rv[i]) continue;
#pragma unroll
    for (int c = 0; c < 8; c++) ls += expf(a1[i][c] + bo[c] - lm);
  }
#pragma unroll
  for (int o2 = 1; o2 < 64; o2 <<= 1) ls += __shfl_xor(ls, o2, 64);
  if ((t & 63) == 0) xr[8 + (t >> 6)] = ls;
  __syncthreads();
  if (t == 0) {
    bstat[2 * blockIdx.x] = lm;
    bstat[2 * blockIdx.x + 1] = xr[8] + xr[9] + xr[10] + xr[11];
  }
}

// ---------- softmax finalize: fold per-block {lm, sum} -> gmax, gsum ----------
__global__ void k_smfin(const float* __restrict__ bstat, int nb,
                        unsigned* __restrict__ scal) {
  __shared__ float s[64];
  int t = threadIdx.x;                // 256 threads
  float lm = -3.4e38f;
  for (int i = t; i < nb; i += 256) lm = fmaxf(lm, bstat[2 * i]);
#pragma unroll
  for (int o = 1; o < 64; o <<= 1) lm = fmaxf(lm, __shfl_xor(lm, o, 64));
  if ((t & 63) == 0) s[t >> 6] = lm;
  __syncthreads();
  float gm = fmaxf(fmaxf(s[0], s[1]), fmaxf(s[2], s[3]));
  float ls = 0.f;
  for (int i = t; i < nb; i += 256) ls += bstat[2 * i + 1] * expf(bstat[2 * i] - gm);
#pragma unroll
  for (int o = 1; o < 64; o <<= 1) ls += __shfl_xor(ls, o, 64);
  if ((t & 63) == 0) s[4 + (t >> 6)] = ls;
  __syncthreads();
  if (t == 0) {
    scal[0] = __float_as_uint(gm);
    scal[1] = __float_as_uint(s[4] + s[5] + s[6] + s[7]);
  }
}

// ---------- GCN aggregation (float4 lanes) ----------
template <int FEAT, bool BIAS, bool RELU, bool PSCALE>
__launch_bounds__(256)
__global__ void k_aggv(const float* __restrict__ g, const int* __restrict__ col,
                       const int* __restrict__ rowptr, const int* __restrict__ deg,
                       const float* __restrict__ dinv, const float* __restrict__ bias,
                       float* __restrict__ out, int N) {
  constexpr int LPN = FEAT / 4;       // lanes per node (float4 each)
  constexpr int NPB = 256 / LPN;      // nodes per block
  int nib = threadIdx.x / LPN;
  int c = threadIdx.x % LPN;
  long v = (long)blockIdx.x * NPB + nib;
  if (v >= N) return;

  const float4* g4 = (const float4*)g;
  float4 acc = g4[v * LPN + c];       // self-loop term
  int start = rowptr[v], dg = deg[v];
  int e = 0;
  while (e < dg) {
    int cnt = min(LPN, dg - e);
    int idx = (c < cnt) ? col[start + e + c] : 0;
    int j = 0;
    for (; j + 4 <= cnt; j += 4) {    // 4 independent 16B gathers in flight
      int u0 = __shfl(idx, j + 0, LPN);
      int u1 = __shfl(idx, j + 1, LPN);
      int u2 = __shfl(idx, j + 2, LPN);
      int u3 = __shfl(idx, j + 3, LPN);
      float4 a0 = g4[(long)u0 * LPN + c];
      float4 a1 = g4[(long)u1 * LPN + c];
      float4 a2 = g4[(long)u2 * LPN + c];
      float4 a3 = g4[(long)u3 * LPN + c];
      acc.x += (a0.x + a1.x) + (a2.x + a3.x);
      acc.y += (a0.y + a1.y) + (a2.y + a3.y);
      acc.z += (a0.z + a1.z) + (a2.z + a3.z);
      acc.w += (a0.w + a1.w) + (a2.w + a3.w);
    }
    for (; j < cnt; j++) {
      int u = __shfl(idx, j, LPN);
      float4 a = g4[(long)u * LPN + c];
      acc.x += a.x; acc.y += a.y; acc.z += a.z; acc.w += a.w;
    }
    e += cnt;
  }
  float dv = dinv[v];
  float4 val;
  val.x = acc.x * dv; val.y = acc.y * dv; val.z = acc.z * dv; val.w = acc.w * dv;
  if (BIAS) {
    float4 b = ((const float4*)bias)[c];
    val.x += b.x; val.y += b.y; val.z += b.z; val.w += b.w;
  }
  if (RELU) {
    val.x = fmaxf(val.x, 0.f); val.y = fmaxf(val.y, 0.f);
    val.z = fmaxf(val.z, 0.f); val.w = fmaxf(val.w, 0.f);
  }
  if (PSCALE) {
    val.x *= dv; val.y *= dv; val.z *= dv; val.w *= dv;
  }
  ((float4*)out)[v * LPN + c] = val;
}

// ---------- softmax normalize (float4) ----------
__global__ void k_smnorm(float4* __restrict__ logit, const unsigned* __restrict__ scal,
                         int total4) {
  float gmax = __uint_as_float(scal[0]);
  float inv = 1.0f / __uint_as_float(scal[1]);
  int i = blockIdx.x * 256 + threadIdx.x;
  if (i < total4) {
    float4 v = logit[i];
    v.x = expf(v.x - gmax) * inv;
    v.y = expf(v.y - gmax) * inv;
    v.z = expf(v.z - gmax) * inv;
    v.w = expf(v.w - gmax) * inv;
    logit[i] = v;
  }
}

// ---------- launch ----------
extern "C" void kernel_launch(void* const* d_in, const int* in_sizes, int n_in,
                              void* d_out, int out_size, void* d_ws, size_t ws_size,
                              hipStream_t stream) {
  const float* x   = (const float*)d_in[0];
  const int*   ei  = (const int*)d_in[1];
  const float* W1  = (const float*)d_in[3];
  const float* b1  = (const float*)d_in[4];
  const float* W2  = (const float*)d_in[5];
  const float* b2  = (const float*)d_in[6];
  const float* Wo1 = (const float*)d_in[7];
  const float* bo1 = (const float*)d_in[8];
  const float* Wo2 = (const float*)d_in[9];
  const float* bo2 = (const float*)d_in[10];

  const int N = in_sizes[0] / 256;   // in_dim = 256
  const int E = in_sizes[1] / 2;
  const int* src = ei;
  const int* dst = ei + E;
  const int NB = (N + BNODES - 1) / BNODES;

  size_t o = 0;
  auto carve = [&](size_t bytes) -> char* {
    char* p = (char*)d_ws + o;
    o += (bytes + 255) & ~(size_t)255;
    return p;
  };
  float* R1     = (float*)carve((size_t)N * 64 * 4);  // g1 | s2
  float* R2     = (float*)carve((size_t)N * 64 * 4);  // epart | p
  int*   col    = (int*)carve((size_t)E * 4);
  int*   deg    = (int*)carve((size_t)N * 4);
  float* dinv   = (float*)carve((size_t)N * 4);
  int*   rowptr = (int*)carve((size_t)N * 4);
  int*   bcnt   = (int*)carve(256 * 4);
  int*   bbase  = (int*)carve(256 * 4);
  int*   bcur   = (int*)carve(256 * 4);
  unsigned* scal = (unsigned*)carve(64);
  float* bstat  = (float*)carve(8192);   // per-block {lm, sum} pairs

  unsigned* epart = (unsigned*)R2;  // dead before p is written
  float* g1 = R1;   // N x 32
  float* p  = R2;   // N x 32: dinv .* relu(layer-1 out)
  float* s2 = R1;   // N x 32: aggregated p (g1 dead)
  float* logits = (float*)d_out;

  // ---- CSR build ----
  k_binit<<<1, 256, 0, stream>>>(bcnt);
  k_bcount<<<512, 256, 0, stream>>>(dst, bcnt, E, NB);
  k_bscan<<<1, 256, 0, stream>>>(bcnt, bbase, bcur, scal, NB);
  k_bpart<<<(E + PCHUNK - 1) / PCHUNK, 256, 0, stream>>>(src, dst, bcur, epart, E, NB);
  k_fine<<<NB, 256, 0, stream>>>(epart, bbase, bcnt, rowptr, deg, dinv, col, N);

  const int g1G = (N + 127) / 128;  // gemm1 / head: 128 rows per block
  const int gA  = (N + 31) / 32;    // agg32: 32 nodes per block

  // layer 1: g1 = dinv .* (x @ W1); p = dinv .* relu(b1 + dinv*(g1[v]+sum g1[u]))
  k_gemm1<<<g1G, 256, 0, stream>>>(x, W1, dinv, g1, N);
  k_aggv<32, true, true, true><<<gA, 256, 0, stream>>>(g1, col, rowptr, deg, dinv, b1, p, N);

  // layer 2 (aggregation commuted before W2): s2 = dinv*(p[v]+sum p[u])
  k_aggv<32, false, false, false><<<gA, 256, 0, stream>>>(p, col, rowptr, deg, dinv, nullptr, s2, N);

  // fused MLP head: s2 -> logits; per-block softmax stats -> bstat
  k_head<<<g1G, 256, 0, stream>>>(s2, W2, b2, Wo1, bo1, Wo2, bo2, logits, N, bstat);

  // softmax: fold block stats, then normalize (float4)
  k_smfin<<<1, 256, 0, stream>>>(bstat, g1G, scal);
  k_smnorm<<<(out_size / 4 + 255) / 256, 256, 0, stream>>>((float4*)logits, scal, out_size / 4);
}